// Round 2
// baseline (136.222 us; speedup 1.0000x reference)
//
#include <hip/hip_runtime.h>
#include <hip/hip_bf16.h>

// Conv 3x3, C_IN=128, C_OUT=256, H=W=256, pad=1, stride=1, batch=1.
// R9: counted-vmcnt software pipeline (T3/T4) on the R8 one-block-per-CU structure.
//     R8 post-mortem: 1 block/CU made every stage drain serial (vmcnt(0) before each
//     barrier, ~2 KB in flight vs ~20 KB needed) -> ~25 us of exposed stall.
//     Now: A plane split into 2x32KB ci-halves, double-buffered (LDS unchanged
//     131.6 KB). 18 half-phases; each issues next half's 4 loads/thread then waits
//     vmcnt(4) -- prefetch stays in flight across the barrier, lands under the
//     ~2.5 kcyc MFMA cluster. B (66 KB) staged 3x, exposed (cheap). Raw s_barrier
//     + sched_barrier(0) fences (rule #18), s_setprio(1) around MFMA (T5).
//     Grid/traffic/XCD-swizzle identical to R8 (FETCH 11 MB, verified).

typedef short bf16x8 __attribute__((ext_vector_type(8)));    // 8 bf16 = 4 VGPRs
typedef float f32x4 __attribute__((ext_vector_type(4)));
typedef unsigned short u16x4 __attribute__((ext_vector_type(4)));
typedef unsigned short u16x8 __attribute__((ext_vector_type(8)));

#define CIN   128
#define COUT  256
#define HH    256
#define WW    256
#define HP    258                 // padded
#define ROWP  (HP * CIN)          // padded row stride in elems = 33024

static __device__ __forceinline__ unsigned short f2bf(float v) {
    __hip_bfloat16 b = __float2bfloat16(v);
    return *reinterpret_cast<unsigned short*>(&b);
}

static __device__ __forceinline__ void gload_lds16(const unsigned short* g, unsigned short* l) {
    __builtin_amdgcn_global_load_lds(
        (const __attribute__((address_space(1))) unsigned int*)g,
        (__attribute__((address_space(3))) unsigned int*)l, 16, 0, 0);
}

// ---------------- dispatch 1: fused prepass (edge zero + wreorder + xpose) -----------
// grid: 1024 blocks x 256 threads (one 64-w xpose tile per block) -- unchanged, verified
__global__ __launch_bounds__(256) void prep_kernel(const float* __restrict__ x,
                                                   const float* __restrict__ w,
                                                   unsigned short* __restrict__ xb,
                                                   unsigned short* __restrict__ wr) {
    int bid = blockIdx.x;
    int t   = threadIdx.x;

    // (a) edge zeroing: blocks 0..64 cover the 16448 vec8 border tasks
    if (bid < 65) {
        int i = bid * 256 + t;
        if (i < 16448) {
            u16x8 z = {0, 0, 0, 0, 0, 0, 0, 0};
            int off;
            if (i < 8256) {
                int r   = (i >= 4128) ? 1 : 0;
                int rem = i - r * 4128;
                off = (r * 257) * ROWP + rem * 8;
            } else {
                int j   = i - 8256;           // 0..8191
                int col = j >> 12;            // 0 or 1
                int rem = j & 4095;
                int hp  = (rem >> 4) + 1;     // 1..256
                int c8  = rem & 15;
                off = hp * ROWP + (col * 257) * CIN + c8 * 8;
            }
            *(u16x8*)(&xb[off]) = z;
        }
    }

    // (b) weight reorder: blocks 0..127, one thread per (co,ci), coalesced
    if (bid < 128) {
        int p = bid * 256 + t;    // 0..32767 = co*128+ci
        const float* src = w + p * 9;
        #pragma unroll
        for (int khw = 0; khw < 9; ++khw)
            wr[khw * (COUT * CIN) + p] = f2bf(src[khw]);
    }

    // (c) xpose: NCHW fp32 -> padded NHWC bf16, one 64-w tile per block
    int h  = bid >> 2;
    int w0 = (bid & 3) * 64;
    __shared__ unsigned short tile[CIN * 72];   // [ci][w], w padded 64->72

    int wq  = t & 15;          // 16 * float4 = 64 w
    int cib = t >> 4;          // 16 ci per pass
    for (int c0 = 0; c0 < CIN; c0 += 16) {
        int ci = c0 + cib;
        float4 v = *(const float4*)(x + ci * (HH * WW) + h * WW + w0 + wq * 4);
        u16x4 p;
        p.x = f2bf(v.x); p.y = f2bf(v.y); p.z = f2bf(v.z); p.w = f2bf(v.w);
        *(u16x4*)(&tile[ci * 72 + wq * 4]) = p;
    }
    __syncthreads();

    for (int it = 0; it < 4; ++it) {
        int idx = it * 256 + t;       // 0..1023
        int ww_ = idx & 63;           // varies within wave (conflict-free LDS reads)
        int c8  = idx >> 6;           // 0..15, wave-uniform
        u16x8 o;
        #pragma unroll
        for (int j = 0; j < 8; ++j)
            o[j] = tile[(c8 * 8 + j) * 72 + ww_];
        int dst = ((h + 1) * HP + (w0 + ww_ + 1)) * CIN + c8 * 8;
        *(u16x8*)(&xb[dst]) = o;
    }
}

// ---------------- dispatch 2: implicit-GEMM MFMA conv, pipelined ---------------------
// block tile: 256 co x 256 spatial (full row h), 8 waves of 64co x 128sp, 1 block/CU.
// 18 half-phases i: khw = i>>1, ci-half = i&1. A half-plane (256 rows x 64 ci, 32 KB)
// double-buffered: iter i issues prefetch of half i+1 (4 loads/thread), waits vmcnt(4)
// (current half + any B landed; prefetch rides across the barrier under the MFMA).
// Bw[col 0..257][ci 0..127]: 16B chunk c of col at slot c^(col&15) (16-slot XOR).
// Ah[row 0..255][ci-half 0..63]: 16B local chunk c of row at slot c^(row&7) (8-slot XOR).
__global__ __launch_bounds__(512, 2) void conv_mfma_kernel(const unsigned short* __restrict__ xb,
                                                           const unsigned short* __restrict__ wr,
                                                           const float* __restrict__ bias,
                                                           float* __restrict__ out) {
    __shared__ unsigned short Bw[258 * 128];       // 66048 B
    __shared__ unsigned short Ah[2][256 * 64];     // 2 x 32768 B ; total LDS 131584 B

    // XCD-chunked bijective swizzle: 256 blocks, 8 XCDs -> 32 consecutive rows per XCD.
    int bid = blockIdx.x;
    int h   = (bid & 7) * 32 + (bid >> 3);     // 0..255, one output row per block

    int t    = threadIdx.x;     // 0..511
    int lane = t & 63;
    int wave = t >> 6;
    int wm   = wave >> 1;       // co quarter (0..3), 64 co each
    int wn   = wave & 1;        // spatial half (0/1), 128 sp each
    int quad = lane >> 4;
    int l16  = lane & 15;

    f32x4 acc[4][8];
    #pragma unroll
    for (int mi = 0; mi < 4; ++mi)
        #pragma unroll
        for (int ni = 0; ni < 8; ++ni)
            acc[mi][ni] = (f32x4){0.f, 0.f, 0.f, 0.f};

    // stage one 32 KB A half-plane (2048 segs of 16B, 4 per thread) into dst
    auto stageA = [&](int idx, unsigned short* dst) {
        int khw_  = idx >> 1;
        int half_ = idx & 1;
        const unsigned short* wsrc = wr + (size_t)khw_ * (COUT * CIN) + half_ * 64;
        #pragma unroll
        for (int it = 0; it < 4; ++it) {
            int seg = it * 512 + t;
            int r   = seg >> 3;
            int s   = seg & 7;
            int c   = s ^ (r & 7);
            gload_lds16(wsrc + r * CIN + c * 8, &dst[seg * 8]);
        }
    };

    // prologue: A half 0 into buffer 0 (4 loads/thread in flight)
    stageA(0, Ah[0]);

    for (int i = 0; i < 18; ++i) {
        int khw  = i >> 1;
        int half = i & 1;
        int kw   = khw % 3;

        // kh boundary: stage full B row (258 cols x 16 chunks = 4128+32 segs).
        // Bw's previous readers finished at iter i-1's trailing barrier.
        if ((i % 6) == 0) {
            const unsigned short* xrow = xb + (size_t)(h + i / 6) * ROWP;
            #pragma unroll
            for (int it = 0; it < 8; ++it) {
                int seg = it * 512 + t;
                int col = seg >> 4;
                int s   = seg & 15;
                int c   = s ^ (col & 15);
                gload_lds16(xrow + col * CIN + c * 8, &Bw[seg * 8]);
            }
            if (t < 32) {
                int seg = 4096 + t;
                int col = seg >> 4;
                int s   = seg & 15;
                int c   = s ^ (col & 15);
                gload_lds16(xrow + col * CIN + c * 8, &Bw[seg * 8]);
            }
        }

        // prefetch next A half (dummy wrap at i=17 keeps the vmcnt count uniform;
        // target buffer's last reader was compute(i-1), protected by its barrier)
        int nxt = (i + 1) % 18;
        stageA(nxt, Ah[nxt & 1]);

        // wait: everything except the 4 newest (the prefetch) has landed
        asm volatile("s_waitcnt vmcnt(4)" ::: "memory");
        __builtin_amdgcn_s_barrier();
        __builtin_amdgcn_sched_barrier(0);

        const unsigned short* Acur = Ah[i & 1];
        __builtin_amdgcn_s_setprio(1);
        #pragma unroll
        for (int kkk = 0; kkk < 2; ++kkk) {
            int lc = kkk * 4 + quad;             // local chunk 0..7 within the half
            int cg = half * 8 + lc;              // global ci chunk 0..15 (for Bw slot)
            bf16x8 af[4], bfr[8];
            #pragma unroll
            for (int mi = 0; mi < 4; ++mi) {
                int row = wm * 64 + mi * 16 + l16;            // row&7 == l16&7
                af[mi] = *(bf16x8*)(&Acur[row * 64 + (lc ^ (l16 & 7)) * 8]);
            }
            #pragma unroll
            for (int ni = 0; ni < 8; ++ni) {
                int col = wn * 128 + ni * 16 + l16 + kw;
                bfr[ni] = *(bf16x8*)(&Bw[col * 128 + (cg ^ (col & 15)) * 8]);
            }
            #pragma unroll
            for (int mi = 0; mi < 4; ++mi)
                #pragma unroll
                for (int ni = 0; ni < 8; ++ni)
                    acc[mi][ni] = __builtin_amdgcn_mfma_f32_16x16x32_bf16(
                        af[mi], bfr[ni], acc[mi][ni], 0, 0, 0);
        }
        __builtin_amdgcn_s_setprio(0);

        // all LDS reads drained before anyone overwrites this buffer (or Bw) next iter
        asm volatile("s_waitcnt lgkmcnt(0)" ::: "memory");
        __builtin_amdgcn_s_barrier();
        __builtin_amdgcn_sched_barrier(0);
    }

    // epilogue: C/D layout col(spatial)=lane&15, row(co)=quad*4+reg
    int sp0 = wn * 128 + l16;
    #pragma unroll
    for (int mi = 0; mi < 4; ++mi) {
        #pragma unroll
        for (int r = 0; r < 4; ++r) {
            int co = wm * 64 + mi * 16 + quad * 4 + r;
            float b = bias[co];
            float* orow = out + (size_t)co * (HH * WW) + h * WW + sp0;
            #pragma unroll
            for (int ni = 0; ni < 8; ++ni)
                orow[ni * 16] = acc[mi][ni][r] + b;
        }
    }
}

extern "C" void kernel_launch(void* const* d_in, const int* in_sizes, int n_in,
                              void* d_out, int out_size, void* d_ws, size_t ws_size,
                              hipStream_t stream) {
    const float* x    = (const float*)d_in[0];   // [1,128,256,256]
    const float* w    = (const float*)d_in[1];   // [256,128,3,3]
    const float* bias = (const float*)d_in[2];   // [256]
    float* out        = (float*)d_out;           // [1,256,256,256]

    unsigned short* xb = (unsigned short*)d_ws;              // 258*258*128 bf16 = 17,040,384 B
    unsigned short* wr = xb + (size_t)HP * HP * CIN;         // 9*256*128 bf16  =    589,824 B

    prep_kernel<<<dim3(1024), dim3(256), 0, stream>>>(x, w, xb, wr);
    conv_mfma_kernel<<<dim3(256), dim3(512), 0, stream>>>(xb, wr, bias, out);
}